// Round 9
// baseline (150.944 us; speedup 1.0000x reference)
//
#include <hip/hip_runtime.h>

// Problem: A=8, B=16, N=M=1024, K=64. u:(A,B,N,K) f32, v:(A,B,M,K) f32.
// out0 = u * (dot(u_row, v_sum) > 0), out1 = v * (dot(v_row, u_sum) > 0)
//
// Round-12: R8 + __launch_bounds__(1024, 4). R8's counters proved BOTH
// halves of the story:
//   FETCH_SIZE = 66.3 MB  -> same-order pair traversal COLLAPSED reads to
//                            the unique volume (R7 theory confirmed).
//   WRITE_SIZE = 129 MB, VGPR_Count = 64, dur 64-70 us
//                         -> allocator capped at 64 VGPRs (default launch
//                            bounds target 8 waves/EU = 2 wg/CU) and spilled
//                            ur[8]/vr[8] to scratch (~62 MB spill writes).
// Fix: declare 4 waves/EU (= exactly our 1 workgroup of 16 waves per CU,
// grid 256 = CU count) -> 512/4 = 128 VGPRs/wave budget. Live set ~100.
// Predicted: VGPR ~96-128, WRITE ~67 MB, FETCH ~67 MB, kernel ~22-24 us.

#define NBATCH 128        // A*B
#define NROW   1024       // N == M
#define KDIM   64
#define ELEMS_PER_TENSOR (128ull * 1024ull * 64ull)  // 8388608

typedef float floatx4 __attribute__((ext_vector_type(4)));  // for nontemporal builtin

__global__ __launch_bounds__(1024, 4)   // 4 waves/EU = 1 wg/CU -> 128 VGPR budget
void fused_sameorder_kernel(const float* __restrict__ u,
                            const float* __restrict__ v,
                            float* __restrict__ out) {
    const int bid   = blockIdx.x;        // 0..255 (1 block/CU)
    // Same-XCD pair swizzle: HW places block bid on XCD (bid & 7); pair
    // blocks (batch, half 0/1) are bids (i, i+8) -> same XCD -> shared L2.
    const int xcd   = bid & 7;
    const int slot  = bid >> 3;          // 0..31
    const int batch = xcd * 16 + (slot >> 1);  // 0..127
    const int half  = slot & 1;          // own rows: [half*512, half*512+512)
    const int tid   = threadIdx.x;       // 0..1023
    const int k4    = tid & 15;          // float4 column group (16 x 4 = 64 cols)
    const int rg    = tid >> 4;          // 0..63 row group
    const int wave  = tid >> 6;          // 0..15

    const size_t boff = (size_t)batch * NROW * KDIM;
    const float4* ub = (const float4*)(u + boff);
    const float4* vb = (const float4*)(v + boff);
    float* ou = out + boff;
    float* ov = out + ELEMS_PER_TENSOR + boff;

    // ---- Phase A: BOTH halves traverse rows 0..1023 in the same order -----
    // Global group gi covers rows rg + 64*gi; gi 0..7 = lower half, 8..15 =
    // upper half. Own rows -> ur/vr registers; all rows -> colsum partials.
    // Pair touches of each line are separated only by CU skew -> second
    // touch hits L2 / merges in flight on the shared XCD (proven: R8 FETCH).
    float4 ur[8], vr[8];
    float4 su = make_float4(0.f, 0.f, 0.f, 0.f);
    float4 sv = make_float4(0.f, 0.f, 0.f, 0.f);

    if (half == 0) {
        #pragma unroll
        for (int i = 0; i < 8; ++i) {     // rows 0..511: own, stash
            size_t io = (size_t)(rg + 64 * i) * 16 + k4;  // wave: 4 rows x 1KB
            ur[i] = ub[io];
            vr[i] = vb[io];
            su.x += ur[i].x; su.y += ur[i].y; su.z += ur[i].z; su.w += ur[i].w;
            sv.x += vr[i].x; sv.y += vr[i].y; sv.z += vr[i].z; sv.w += vr[i].w;
        }
        #pragma unroll
        for (int i = 8; i < 16; ++i) {    // rows 512..1023: other, accum only
            size_t io = (size_t)(rg + 64 * i) * 16 + k4;
            float4 a = ub[io];
            float4 b = vb[io];
            su.x += a.x; su.y += a.y; su.z += a.z; su.w += a.w;
            sv.x += b.x; sv.y += b.y; sv.z += b.z; sv.w += b.w;
        }
    } else {
        #pragma unroll
        for (int i = 0; i < 8; ++i) {     // rows 0..511: other, accum only
            size_t io = (size_t)(rg + 64 * i) * 16 + k4;
            float4 a = ub[io];
            float4 b = vb[io];
            su.x += a.x; su.y += a.y; su.z += a.z; su.w += a.w;
            sv.x += b.x; sv.y += b.y; sv.z += b.z; sv.w += b.w;
        }
        #pragma unroll
        for (int i = 0; i < 8; ++i) {     // rows 512..1023: own, stash
            size_t io = (size_t)(rg + 64 * (i + 8)) * 16 + k4;
            ur[i] = ub[io];
            vr[i] = vb[io];
            su.x += ur[i].x; su.y += ur[i].y; su.z += ur[i].z; su.w += ur[i].w;
            sv.x += vr[i].x; sv.y += vr[i].y; sv.z += vr[i].z; sv.w += vr[i].w;
        }
    }

    // ---- Reduce: shfl across the 4 row-groups within each wave ------------
    su.x += __shfl_xor(su.x, 16); su.y += __shfl_xor(su.y, 16);
    su.z += __shfl_xor(su.z, 16); su.w += __shfl_xor(su.w, 16);
    su.x += __shfl_xor(su.x, 32); su.y += __shfl_xor(su.y, 32);
    su.z += __shfl_xor(su.z, 32); su.w += __shfl_xor(su.w, 32);
    sv.x += __shfl_xor(sv.x, 16); sv.y += __shfl_xor(sv.y, 16);
    sv.z += __shfl_xor(sv.z, 16); sv.w += __shfl_xor(sv.w, 16);
    sv.x += __shfl_xor(sv.x, 32); sv.y += __shfl_xor(sv.y, 32);
    sv.z += __shfl_xor(sv.z, 32); sv.w += __shfl_xor(sv.w, 32);

    __shared__ float4 red_u[16][16];   // [wave][k4]
    __shared__ float4 red_v[16][16];
    if ((tid & 63) < 16) {             // lanes 0..15 hold k4 = lane
        red_u[wave][k4] = su;
        red_v[wave][k4] = sv;
    }
    __syncthreads();                   // the ONLY barrier

    // all-thread self-reduce; same-k4 threads read same address (broadcast)
    float4 us = make_float4(0.f, 0.f, 0.f, 0.f);  // u colsum (masks v rows)
    float4 vs = make_float4(0.f, 0.f, 0.f, 0.f);  // v colsum (masks u rows)
    #pragma unroll
    for (int w = 0; w < 16; ++w) {
        float4 a = red_u[w][k4];
        float4 b = red_v[w][k4];
        us.x += a.x; us.y += a.y; us.z += a.z; us.w += a.w;
        vs.x += b.x; vs.y += b.y; vs.z += b.z; vs.w += b.w;
    }

    // ---- Phase B: mask own half from registers, streaming NT stores -------
    const int r_own0 = half * 512 + rg;
    #pragma unroll
    for (int i = 0; i < 8; ++i) {
        size_t io = (size_t)(r_own0 + 64 * i) * 16 + k4;

        float pu = ur[i].x * vs.x + ur[i].y * vs.y + ur[i].z * vs.z + ur[i].w * vs.w;
        pu += __shfl_xor(pu, 1);
        pu += __shfl_xor(pu, 2);
        pu += __shfl_xor(pu, 4);
        pu += __shfl_xor(pu, 8);       // full 64-col dot across the 16 k4 lanes
        float mu = (pu > 0.f) ? 1.f : 0.f;
        floatx4 outu = { ur[i].x * mu, ur[i].y * mu, ur[i].z * mu, ur[i].w * mu };
        __builtin_nontemporal_store(outu, (floatx4*)(ou + io * 4));

        float pv = vr[i].x * us.x + vr[i].y * us.y + vr[i].z * us.z + vr[i].w * us.w;
        pv += __shfl_xor(pv, 1);
        pv += __shfl_xor(pv, 2);
        pv += __shfl_xor(pv, 4);
        pv += __shfl_xor(pv, 8);
        float mv = (pv > 0.f) ? 1.f : 0.f;
        floatx4 outv = { vr[i].x * mv, vr[i].y * mv, vr[i].z * mv, vr[i].w * mv };
        __builtin_nontemporal_store(outv, (floatx4*)(ov + io * 4));
    }
}

extern "C" void kernel_launch(void* const* d_in, const int* in_sizes, int n_in,
                              void* d_out, int out_size, void* d_ws, size_t ws_size,
                              hipStream_t stream) {
    const float* u = (const float*)d_in[0];
    const float* v = (const float*)d_in[1];
    float* out = (float*)d_out;

    fused_sameorder_kernel<<<dim3(256), dim3(1024), 0, stream>>>(u, v, out);
}

// Round 11
// 117.457 us; speedup vs baseline: 1.2851x; 1.2851x over previous
//
#include <hip/hip_runtime.h>

// Problem: A=8, B=16, N=M=1024, K=64. u:(A,B,N,K) f32, v:(A,B,M,K) f32.
// out0 = u * (dot(u_row, v_sum) > 0), out1 = v * (dot(v_row, u_sum) > 0)
//
// Round-14: ZERO-RETENTION 3-phase stream. Counter history:
//   R8: same-order pair traversal -> FETCH collapsed to 66.3 MB (= unique
//       volume). PROVEN, kept.
//   R8/R9: WRITE = 129 MB, VGPR_Count = 64 -> allocator pins this kernel at
//       64 VGPRs regardless of __launch_bounds__(1024,4) (R9) and spills the
//       64 data VGPRs of ur[8]+vr[8] (~62 MB scratch writes, dur ~67 us).
//   R10 (waves_per_eu attr) died to infra; not re-rolling the allocator
//       dice — restructure so the live set fits 64 VGPRs BY DESIGN.
// Schedule (no register/LDS retention of tensor data at all):
//   A: stream ALL of v same-order -> v colsum only. 16 independent
//      loads/thread, max MLP.                          [HBM: 33.5 MB R]
//   B: stream ALL of u same-order: own rows -> mask(vs)+NT-store immediately
//      + accumulate; other rows -> accumulate only.    [33.5 R + 33.5 W]
//   C: RE-READ own v rows, mask(us), NT-store. Inputs (128 MB) are
//      L3-resident (256 MB Infinity Cache); v was pulled through L3 in
//      phase A and NT stores don't allocate -> re-read is L3-served,
//      zero HBM, overlaps the v writes.                [33.5 W + L3 R]
// HBM total = 134 MB = 21.3 us floor; predicted kernel ~23-26 us,
// WRITE_SIZE ~67 MB (spill gone), VGPR <= 64 no-spill.
// Bounded downside: if L3 evicts v, +5.3 us -> ~28 us ~= R1's best.

#define NBATCH 128        // A*B
#define NROW   1024       // N == M
#define KDIM   64
#define ELEMS_PER_TENSOR (128ull * 1024ull * 64ull)  // 8388608

typedef float floatx4 __attribute__((ext_vector_type(4)));  // for nontemporal builtin

__global__ __launch_bounds__(1024)
void fused_stream_kernel(const float* __restrict__ u,
                         const float* __restrict__ v,
                         float* __restrict__ out) {
    const int bid   = blockIdx.x;        // 0..255 (1 block/CU)
    // Same-XCD pair swizzle: HW places block bid on XCD (bid & 7); pair
    // blocks (batch, half 0/1) are bids (i, i+8) -> same XCD -> shared L2.
    const int xcd   = bid & 7;
    const int slot  = bid >> 3;          // 0..31
    const int batch = xcd * 16 + (slot >> 1);  // 0..127
    const int half  = slot & 1;          // own rows: [half*512, half*512+512)
    const int tid   = threadIdx.x;       // 0..1023
    const int k4    = tid & 15;          // float4 column group (16 x 4 = 64 cols)
    const int rg    = tid >> 4;          // 0..63 row group
    const int wave  = tid >> 6;          // 0..15

    const size_t boff = (size_t)batch * NROW * KDIM;
    const float4* ub = (const float4*)(u + boff);
    const float4* vb = (const float4*)(v + boff);
    float* ou = out + boff;
    float* ov = out + ELEMS_PER_TENSOR + boff;

    __shared__ float4 red_v[16][16];   // [wave][k4]
    __shared__ float4 red_u[16][16];

    // ======== Phase A: stream ALL of v, same order, colsum only ===========
    // Global group gi covers rows rg + 64*gi. Both pair-blocks walk gi
    // 0..15 in the same order -> duplicate touches L2-collapse (proven R8).
    float4 sv = make_float4(0.f, 0.f, 0.f, 0.f);
    #pragma unroll
    for (int i = 0; i < 16; ++i) {
        size_t io = (size_t)(rg + 64 * i) * 16 + k4;   // wave: 4 rows x 1KB
        float4 b = vb[io];
        sv.x += b.x; sv.y += b.y; sv.z += b.z; sv.w += b.w;
    }
    sv.x += __shfl_xor(sv.x, 16); sv.y += __shfl_xor(sv.y, 16);
    sv.z += __shfl_xor(sv.z, 16); sv.w += __shfl_xor(sv.w, 16);
    sv.x += __shfl_xor(sv.x, 32); sv.y += __shfl_xor(sv.y, 32);
    sv.z += __shfl_xor(sv.z, 32); sv.w += __shfl_xor(sv.w, 32);
    if ((tid & 63) < 16)               // lanes 0..15 hold k4 = lane
        red_v[wave][k4] = sv;
    __syncthreads();                   // barrier 1

    // all-thread self-reduce; same-k4 threads read same address (broadcast)
    float4 vs = make_float4(0.f, 0.f, 0.f, 0.f);  // v colsum (masks u rows)
    #pragma unroll
    for (int w = 0; w < 16; ++w) {
        float4 t = red_v[w][k4];
        vs.x += t.x; vs.y += t.y; vs.z += t.z; vs.w += t.w;
    }

    // ======== Phase B: stream ALL of u, same order; own rows masked ========
    float4 su = make_float4(0.f, 0.f, 0.f, 0.f);
    if (half == 0) {
        #pragma unroll
        for (int i = 0; i < 8; ++i) {     // rows 0..511: own -> mask + store
            size_t io = (size_t)(rg + 64 * i) * 16 + k4;
            float4 a = ub[io];
            su.x += a.x; su.y += a.y; su.z += a.z; su.w += a.w;
            float pu = a.x * vs.x + a.y * vs.y + a.z * vs.z + a.w * vs.w;
            pu += __shfl_xor(pu, 1);
            pu += __shfl_xor(pu, 2);
            pu += __shfl_xor(pu, 4);
            pu += __shfl_xor(pu, 8);      // full 64-col dot across 16 k4 lanes
            float mu = (pu > 0.f) ? 1.f : 0.f;
            floatx4 outu = { a.x * mu, a.y * mu, a.z * mu, a.w * mu };
            __builtin_nontemporal_store(outu, (floatx4*)(ou + io * 4));
        }
        #pragma unroll
        for (int i = 8; i < 16; ++i) {    // rows 512..1023: other -> accum
            size_t io = (size_t)(rg + 64 * i) * 16 + k4;
            float4 a = ub[io];
            su.x += a.x; su.y += a.y; su.z += a.z; su.w += a.w;
        }
    } else {
        #pragma unroll
        for (int i = 0; i < 8; ++i) {     // rows 0..511: other -> accum
            size_t io = (size_t)(rg + 64 * i) * 16 + k4;
            float4 a = ub[io];
            su.x += a.x; su.y += a.y; su.z += a.z; su.w += a.w;
        }
        #pragma unroll
        for (int i = 0; i < 8; ++i) {     // rows 512..1023: own -> mask+store
            size_t io = (size_t)(rg + 64 * (i + 8)) * 16 + k4;
            float4 a = ub[io];
            su.x += a.x; su.y += a.y; su.z += a.z; su.w += a.w;
            float pu = a.x * vs.x + a.y * vs.y + a.z * vs.z + a.w * vs.w;
            pu += __shfl_xor(pu, 1);
            pu += __shfl_xor(pu, 2);
            pu += __shfl_xor(pu, 4);
            pu += __shfl_xor(pu, 8);
            float mu = (pu > 0.f) ? 1.f : 0.f;
            floatx4 outu = { a.x * mu, a.y * mu, a.z * mu, a.w * mu };
            __builtin_nontemporal_store(outu, (floatx4*)(ou + io * 4));
        }
    }

    su.x += __shfl_xor(su.x, 16); su.y += __shfl_xor(su.y, 16);
    su.z += __shfl_xor(su.z, 16); su.w += __shfl_xor(su.w, 16);
    su.x += __shfl_xor(su.x, 32); su.y += __shfl_xor(su.y, 32);
    su.z += __shfl_xor(su.z, 32); su.w += __shfl_xor(su.w, 32);
    if ((tid & 63) < 16)
        red_u[wave][k4] = su;
    __syncthreads();                   // barrier 2

    float4 us = make_float4(0.f, 0.f, 0.f, 0.f);  // u colsum (masks v rows)
    #pragma unroll
    for (int w = 0; w < 16; ++w) {
        float4 t = red_u[w][k4];
        us.x += t.x; us.y += t.y; us.z += t.z; us.w += t.w;
    }

    // ======== Phase C: re-read own v rows (L3-served), mask, store =========
    const int r_own0 = half * 512 + rg;
    #pragma unroll
    for (int i = 0; i < 8; ++i) {
        size_t io = (size_t)(r_own0 + 64 * i) * 16 + k4;
        float4 b = vb[io];                // L3-resident since phase A
        float pv = b.x * us.x + b.y * us.y + b.z * us.z + b.w * us.w;
        pv += __shfl_xor(pv, 1);
        pv += __shfl_xor(pv, 2);
        pv += __shfl_xor(pv, 4);
        pv += __shfl_xor(pv, 8);
        float mv = (pv > 0.f) ? 1.f : 0.f;
        floatx4 outv = { b.x * mv, b.y * mv, b.z * mv, b.w * mv };
        __builtin_nontemporal_store(outv, (floatx4*)(ov + io * 4));
    }
}

extern "C" void kernel_launch(void* const* d_in, const int* in_sizes, int n_in,
                              void* d_out, int out_size, void* d_ws, size_t ws_size,
                              hipStream_t stream) {
    const float* u = (const float*)d_in[0];
    const float* v = (const float*)d_in[1];
    float* out = (float*)d_out;

    fused_stream_kernel<<<dim3(256), dim3(1024), 0, stream>>>(u, v, out);
}